// Round 7
// baseline (162.058 us; speedup 1.0000x reference)
//
#include <hip/hip_runtime.h>
#include <hip/hip_bf16.h>
#include <stdint.h>

typedef unsigned short u16;
typedef signed char i8;

#define D_INNER 2048
#define D_OUTER 2048
#define MROWS   8192                 // B*S = 2*4096
#define W_ELEMS (D_OUTER * D_INNER)  // 4194304
#define NPART   1024                 // absmean partial blocks

// ---- gemm geometry: 256x256 tile, BK=128 i8, 4 waves x (128x128) out ----
#define BM 256
#define BN 256
#define BK 128
#define NKT (D_INNER / BK)           // 16 K-tiles
#define SLOT_BYTES 65536             // A 32KB + B 32KB
#define LDS_TOTAL  131072            // 2 slots

typedef __attribute__((ext_vector_type(4))) float f32x4;
typedef __attribute__((ext_vector_type(4))) int   i32x4;
typedef __attribute__((ext_vector_type(16))) int  i32x16;

// ------- 1) prep (FROZEN from R5/R6): RMSNorm one wave/row + |w| partials -------
__global__ __launch_bounds__(256) void prep_kernel(const float* __restrict__ x,
                            const float* __restrict__ g,
                            const float* __restrict__ w,
                            i8* __restrict__ xn, float* __restrict__ srow,
                            float* __restrict__ partials) {
  int t = threadIdx.x;
  int lane = t & 63, wvi = t >> 6;

  if (blockIdx.x >= MROWS / 4) {
    __shared__ float red[4];
    int p = blockIdx.x - MROWS / 4;
    int base = p * 1024;
    float s = 0.f;
#pragma unroll
    for (int r = 0; r < 4; ++r) {
      f32x4 v = ((const f32x4*)w)[base + r * 256 + t];
      s += fabsf(v[0]) + fabsf(v[1]) + fabsf(v[2]) + fabsf(v[3]);
    }
    for (int off = 32; off; off >>= 1) s += __shfl_down(s, off, 64);
    if (lane == 0) red[wvi] = s;
    __syncthreads();
    if (t == 0) partials[p] = red[0] + red[1] + red[2] + red[3];
    return;
  }

  int row = blockIdx.x * 4 + wvi;
  const f32x4* xr = (const f32x4*)(x + (size_t)row * D_INNER);
  const f32x4* gr = (const f32x4*)g;
  i8* xo = xn + (size_t)row * D_INNER;

  f32x4 v[8], gv[8];
#pragma unroll
  for (int r = 0; r < 8; ++r) {
    v[r]  = __builtin_nontemporal_load(&xr[lane + r * 64]);
    gv[r] = gr[lane + r * 64];
  }
  float s = 0.f, m = 0.f;
#pragma unroll
  for (int r = 0; r < 8; ++r) {
    s += v[r][0]*v[r][0] + v[r][1]*v[r][1] + v[r][2]*v[r][2] + v[r][3]*v[r][3];
    m = fmaxf(m, fmaxf(fmaxf(fabsf(v[r][0]*gv[r][0]), fabsf(v[r][1]*gv[r][1])),
                       fmaxf(fabsf(v[r][2]*gv[r][2]), fabsf(v[r][3]*gv[r][3]))));
  }
#pragma unroll
  for (int off = 32; off; off >>= 1) {
    s += __shfl_xor(s, off, 64);
    m = fmaxf(m, __shfl_xor(m, off, 64));
  }
  float invr = 1.0f / sqrtf(s * (1.0f / (float)D_INNER) + 1e-6f);
  float amax = fmaxf(m * invr, 1e-12f);
  float step = amax * (1.0f / 127.0f);
  float qs   = 127.0f / amax;
  if (lane == 0) srow[row] = step;

#pragma unroll
  for (int r = 0; r < 8; ++r) {
    char4 q;
    float qv;
    qv = fminf(127.f, fmaxf(-127.f, rintf(v[r][0]*invr*gv[r][0]*qs))); q.x = (i8)(int)qv;
    qv = fminf(127.f, fmaxf(-127.f, rintf(v[r][1]*invr*gv[r][1]*qs))); q.y = (i8)(int)qv;
    qv = fminf(127.f, fmaxf(-127.f, rintf(v[r][2]*invr*gv[r][2]*qs))); q.z = (i8)(int)qv;
    qv = fminf(127.f, fmaxf(-127.f, rintf(v[r][3]*invr*gv[r][3]*qs))); q.w = (i8)(int)qv;
    ((char4*)xo)[lane + r * 64] = q;
  }
}

// ------- 2) ternary quantize (FROZEN) -------
__global__ __launch_bounds__(256) void quant_kernel(const float* __restrict__ w,
                             const float* __restrict__ partials,
                             float* __restrict__ gamma_out, i8* __restrict__ wq) {
  f32x4 pv = ((const f32x4*)partials)[threadIdx.x];
  double d = (double)pv[0] + (double)pv[1] + (double)pv[2] + (double)pv[3];
  for (int off = 32; off; off >>= 1) d += __shfl_down(d, off, 64);
  __shared__ double red[4];
  int lane = threadIdx.x & 63, wvi = threadIdx.x >> 6;
  if (lane == 0) red[wvi] = d;
  __syncthreads();
  double total = red[0] + red[1] + red[2] + red[3];
  float gamma = (float)(total * (1.0 / (double)W_ELEMS));
  float inv = 1.0f / (gamma + 1e-8f);
  if (blockIdx.x == 0 && threadIdx.x == 0) *gamma_out = gamma;

  int tid = blockIdx.x * blockDim.x + threadIdx.x;
  int stride = gridDim.x * blockDim.x;
  for (int i = tid; i < W_ELEMS / 4; i += stride) {
    f32x4 v = ((const f32x4*)w)[i];
    char4 q;
    q.x = (i8)(int)fminf(1.f, fmaxf(-1.f, rintf(v[0] * inv)));
    q.y = (i8)(int)fminf(1.f, fmaxf(-1.f, rintf(v[1] * inv)));
    q.z = (i8)(int)fminf(1.f, fmaxf(-1.f, rintf(v[2] * inv)));
    q.w = (i8)(int)fminf(1.f, fmaxf(-1.f, rintf(v[3] * inv)));
    ((char4*)wq)[i] = q;
  }
}

// ------- 3) i8 GEMM: 4 waves x (128x128), in-wave software pipeline -------
// R6 structure (verified PASS) with the schedule freed: no setprio (T5's
// prereq -- wave role-split -- is absent at 1 wave/SIMD; the pair was also
// pinning the scheduler), A-fragment reads prefetched one phase ahead
// (af0/af1 rotation), full 16-GLDS stage issued in one batch right after
// the publish barrier so it sinks under the whole compute region. At
// 1 wave/SIMD the ONLY latency hiding is in-wave ILP -- give the compiler
// the dependency slack and let it emit counted lgkmcnt.
#define GLDS(SRC, DST) __builtin_amdgcn_global_load_lds( \
    (const __attribute__((address_space(1))) void*)(SRC), \
    (__attribute__((address_space(3))) void*)(DST), 16, 0, 0)
#define WAITVM(N) asm volatile("s_waitcnt vmcnt(" #N ")")
#define BAR()     __builtin_amdgcn_s_barrier()
#define FENCE()   __builtin_amdgcn_sched_barrier(0)

__global__ __launch_bounds__(256, 1) void gemm_bt(const i8* __restrict__ A,
                                                  const i8* __restrict__ Bw,
                                                  const float* __restrict__ gamma_p,
                                                  const float* __restrict__ srow,
                                                  float* __restrict__ C) {
  extern __shared__ i8 lds[];   // slot s: A at s*65536, B at s*65536+32768

  int f   = blockIdx.y * 8 + blockIdx.x;   // 0..255, x-fastest
  int xcd = f & 7;
  int gg  = f >> 3;
  int orig = xcd * 32 + gg;
  int nb  = orig & 7;
  int mb  = orig >> 3;
  int bm0 = mb * BM;
  int bn0 = nb * BN;

  int tid  = threadIdx.x;
  int lane = tid & 63;
  int wv   = tid >> 6;          // 0..3
  int wr   = wv >> 1;           // 0..1 -> rows wr*128
  int wc   = wv & 1;            // 0..1 -> cols wc*128
  int l31  = lane & 31;
  int hi   = lane >> 5;

  const i8* Ag = A  + (size_t)bm0 * D_INNER;
  const i8* Bg = Bw + (size_t)bn0 * D_INNER;

  // staging decode (verified R3/R6): round rr covers rows rr*32+(tid>>3);
  // src chunk XOR'd by row&7 (== (tid>>3)&7); dst linear rr*4096 + tid*16.
  size_t srcx = (size_t)(tid >> 3) * D_INNER + (((tid & 7) ^ ((tid >> 3) & 7)) << 4);

  // read addressing (verified)
  int rdA = (wr * 128 + l31) * BK;            // + mi*4096 + swz[ks]
  int rdB = 32768 + (wc * 128 + l31) * BK;    // + nj*4096 + swz[ks]
  int swz[4];
#pragma unroll
  for (int ks = 0; ks < 4; ++ks)
    swz[ks] = (((ks << 1) | hi) ^ (l31 & 7)) << 4;

  i32x16 acc[4][4] = {};

#define GLDS_A(T_, RR, S_) \
    GLDS(Ag + srcx + (size_t)(RR) * (32 * D_INNER) + (size_t)(T_) * BK, \
         lds + (S_) * SLOT_BYTES + (RR) * 4096 + tid * 16)
#define GLDS_B(T_, RR, S_) \
    GLDS(Bg + srcx + (size_t)(RR) * (32 * D_INNER) + (size_t)(T_) * BK, \
         lds + (S_) * SLOT_BYTES + 32768 + (RR) * 4096 + tid * 16)

#define MFMA16(P_, AF) do { \
    _Pragma("unroll") for (int ks = 0; ks < 4; ++ks) \
      _Pragma("unroll") for (int nj = 0; nj < 4; ++nj) \
        acc[P_][nj] = __builtin_amdgcn_mfma_i32_32x32x32_i8( \
            AF[ks], bf_[ks][nj], acc[P_][nj], 0, 0, 0); \
  } while (0)

#define TILE(T_, DS_) do { \
    WAITVM(0);               /* tile T_'s 16 loads landed (t+1 not issued) */ \
    FENCE(); \
    BAR();                   /* publish across waves; slot (T_+1)&1 free */ \
    FENCE(); \
    const i8* sl_ = lds + ((T_) & 1) * SLOT_BYTES; \
    i32x4 bf_[4][4]; \
    _Pragma("unroll") for (int ks = 0; ks < 4; ++ks) \
      _Pragma("unroll") for (int nj = 0; nj < 4; ++nj) \
        bf_[ks][nj] = *(const i32x4*)(sl_ + rdB + nj * 4096 + swz[ks]); \
    i32x4 af0[4], af1[4]; \
    _Pragma("unroll") for (int ks = 0; ks < 4; ++ks) \
      af0[ks] = *(const i32x4*)(sl_ + rdA + swz[ks]); \
    if (DS_) { \
      _Pragma("unroll") for (int rr = 0; rr < 8; ++rr) { \
        GLDS_A((T_) + 1, rr, ((T_) + 1) & 1); \
        GLDS_B((T_) + 1, rr, ((T_) + 1) & 1); \
      } \
    } \
    _Pragma("unroll") for (int ks = 0; ks < 4; ++ks) \
      af1[ks] = *(const i32x4*)(sl_ + rdA + 1 * 4096 + swz[ks]); \
    MFMA16(0, af0); \
    _Pragma("unroll") for (int ks = 0; ks < 4; ++ks) \
      af0[ks] = *(const i32x4*)(sl_ + rdA + 2 * 4096 + swz[ks]); \
    MFMA16(1, af1); \
    _Pragma("unroll") for (int ks = 0; ks < 4; ++ks) \
      af1[ks] = *(const i32x4*)(sl_ + rdA + 3 * 4096 + swz[ks]); \
    MFMA16(2, af0); \
    MFMA16(3, af1); \
  } while (0)

  // prologue: full tile 0 into slot 0
#pragma unroll
  for (int rr = 0; rr < 8; ++rr) { GLDS_A(0, rr, 0); GLDS_B(0, rr, 0); }

  for (int t = 0; t < NKT - 1; ++t)
    TILE(t, 1);
  TILE(NKT - 1, 0);

  // epilogue: C/D 32x32 layout: col = lane&31, row = (reg&3) + 8*(reg>>2) + 4*hi
  float gamma = *gamma_p;
#pragma unroll
  for (int mi = 0; mi < 4; ++mi) {
    int rbase = bm0 + wr * 128 + mi * 32 + hi * 4;
    f32x4 sg[4];
#pragma unroll
    for (int q = 0; q < 4; ++q) {
      f32x4 sv = *(const f32x4*)(srow + rbase + q * 8);
      sg[q] = sv * gamma;
    }
#pragma unroll
    for (int nj = 0; nj < 4; ++nj) {
      int colb = bn0 + wc * 128 + nj * 32 + l31;
      i32x16 v = acc[mi][nj];
      float* cp = C + (size_t)rbase * D_OUTER + colb;
#pragma unroll
      for (int q = 0; q < 4; ++q)
#pragma unroll
        for (int rr = 0; rr < 4; ++rr)
          cp[(size_t)(q * 8 + rr) * D_OUTER] = (float)v[q * 4 + rr] * sg[q][rr];
    }
  }
}

extern "C" void kernel_launch(void* const* d_in, const int* in_sizes, int n_in,
                              void* d_out, int out_size, void* d_ws, size_t ws_size,
                              hipStream_t stream) {
  const float* x = (const float*)d_in[0];   // [2,4096,2048]
  const float* w = (const float*)d_in[1];   // [2048,2048]
  const float* g = (const float*)d_in[2];   // [2048]
  float* out = (float*)d_out;               // [2,4096,2048] fp32

  float* gamma_p  = (float*)d_ws;                                  // 1 float
  float* partials = (float*)((char*)d_ws + 64);                    // 1024 floats
  float* srow     = (float*)((char*)d_ws + 8192);                  // 8192 floats
  i8* xn = (i8*)((char*)d_ws + 8192 + 32768);                      // 16 MB
  i8* wq = (i8*)((char*)d_ws + 8192 + 32768 + (size_t)MROWS * D_INNER);  // 4 MB

  static bool attr_set = false;
  if (!attr_set) {
    (void)hipFuncSetAttribute(reinterpret_cast<const void*>(&gemm_bt),
                              hipFuncAttributeMaxDynamicSharedMemorySize, LDS_TOTAL);
    attr_set = true;
  }

  prep_kernel<<<MROWS / 4 + NPART, 256, 0, stream>>>(x, g, w, xn, srow, partials);
  quant_kernel<<<2048, 256, 0, stream>>>(w, partials, gamma_p, wq);
  gemm_bt<<<dim3(8, 32), 256, LDS_TOTAL, stream>>>(xn, wq, gamma_p, srow, out);
}